// Round 1
// baseline (78.721 us; speedup 1.0000x reference)
//
#include <hip/hip_runtime.h>

#define NB 4
#define NC 32
#define HW 4096
#define NW 64

#define PPT 4              // pixels per thread
#define TPB 256            // threads per block
#define PPB (PPT * TPB)    // 1024 pixels per block
#define TILES (HW / PPB)   // 4 tiles per (b,c)

__global__ __launch_bounds__(TPB) void rbf_kernel(
    const float* __restrict__ x_real, const float* __restrict__ x_imag,
    const float* __restrict__ w_real, const float* __restrict__ w_imag,
    const float* __restrict__ b_real, const float* __restrict__ b_imag,
    const float* __restrict__ mu_real, const float* __restrict__ mu_imag,
    const float* __restrict__ stddev, float* __restrict__ out)
{
    const int bc   = blockIdx.x / TILES;      // b*NC + c
    const int tile = blockIdx.x % TILES;
    const int c    = bc % NC;
    const int t    = threadIdx.x;

    __shared__ float s_mu_r[NW], s_mu_i[NW], s_coef[NW], s_wr[NW], s_wi[NW];
    if (t < NW) {
        s_mu_r[t] = mu_real[t];
        s_mu_i[t] = mu_imag[t];
        // exp(-(d2)/(2*sigma)) = exp2(d2 * (-log2(e)/(2*sigma)))
        s_coef[t] = -1.4426950408889634f / (2.0f * stddev[t]);
        s_wr[t]   = w_real[c * NW + t];
        s_wi[t]   = w_imag[c * NW + t];
    }
    __syncthreads();

    const int base = bc * HW + tile * PPB + t;  // stride-TPB pixel layout: coalesced

    float xr[PPT], xi[PPT], ar[PPT], ai[PPT];
#pragma unroll
    for (int p = 0; p < PPT; ++p) {
        xr[p] = x_real[base + p * TPB];
        xi[p] = x_imag[base + p * TPB];
        ar[p] = 0.0f;
        ai[p] = 0.0f;
    }

#pragma unroll 8
    for (int k = 0; k < NW; ++k) {
        const float mr = s_mu_r[k];
        const float mi = s_mu_i[k];
        const float cf = s_coef[k];
        const float wr = s_wr[k];
        const float wi = s_wi[k];
#pragma unroll
        for (int p = 0; p < PPT; ++p) {
            float dr  = xr[p] - mr;
            float di  = xi[p] - mi;
            float d2  = fmaf(di, di, dr * dr);
            float rbf = __builtin_amdgcn_exp2f(d2 * cf);
            ar[p] = fmaf(rbf, wr, ar[p]);
            ai[p] = fmaf(rbf, wi, ai[p]);
        }
    }

    const float br = b_real[c];
    const float bi = b_imag[c];
    float2* __restrict__ out2 = reinterpret_cast<float2*>(out);
#pragma unroll
    for (int p = 0; p < PPT; ++p) {
        out2[base + p * TPB] = make_float2(ar[p] + br, ai[p] + bi);
    }
}

extern "C" void kernel_launch(void* const* d_in, const int* in_sizes, int n_in,
                              void* d_out, int out_size, void* d_ws, size_t ws_size,
                              hipStream_t stream) {
    const float* x_real  = (const float*)d_in[0];
    const float* x_imag  = (const float*)d_in[1];
    const float* w_real  = (const float*)d_in[2];
    const float* w_imag  = (const float*)d_in[3];
    const float* b_real  = (const float*)d_in[4];
    const float* b_imag  = (const float*)d_in[5];
    const float* mu_real = (const float*)d_in[6];
    const float* mu_imag = (const float*)d_in[7];
    const float* stddev  = (const float*)d_in[8];
    float* out = (float*)d_out;

    const int grid = NB * NC * TILES;  // 512 blocks
    rbf_kernel<<<grid, TPB, 0, stream>>>(x_real, x_imag, w_real, w_imag,
                                         b_real, b_imag, mu_real, mu_imag,
                                         stddev, out);
}